// Round 15
// baseline (259.423 us; speedup 1.0000x reference)
//
#include <hip/hip_runtime.h>

// VQ argmin: 1-pass f16 SCREEN on matrix cores (xh.ch only, score error
// sigma ~9e-3) + exact fp32 parallel rescan for tokens whose screen
// best2-best1 gap < MARGIN (expected ~1.5% of tokens).
// R14 (on R13, vq=112us best): WAVE-PRIVATE K-loop sync. The B slice bufs
// are wave-private (each wave stages only its own 64 codes into its own
// 16KB), so the 64 block-wide barrier drains were pure convoy overhead.
// Replaced with wave-local waits: lgkmcnt(0) (my prior-tile ds_reads done)
// before DMA overwrite, vmcnt(0) (my 16 loads landed) before consume, each
// + sched_barrier(0) (guide rule 18). NOT R3's counted-vmcnt ring (raced):
// full drains, single-buffered, same per-tile ordering as the barrier
// version minus cross-wave lockstep. The one necessary block barrier
// (after ahi preload, protecting the aliased As region) stays.
// Fold/reduces/rescan/apply byte-identical to R13.

#define M_TOK  32768
#define DIM    128
#define KCODES 8192
#define BM     64
#define NT     (KCODES / 256)   // 32 n-tiles per block
#define MARGIN 0.10f            // ~8 sigma of screen pair error; gap scale 6.9
#define RTG    8                // tokens per rescan group

typedef _Float16 half8v __attribute__((ext_vector_type(8)));
typedef float float4v __attribute__((ext_vector_type(4)));

union H2U { _Float16 h; unsigned short u; };
__device__ __forceinline__ unsigned short f2h_bits(_Float16 h) {
  H2U c; c.h = h; return c.u;
}

__device__ __forceinline__ void gload_lds16(const void* g, void* l) {
  __builtin_amdgcn_global_load_lds(
      (const __attribute__((address_space(1))) unsigned int*)g,
      (__attribute__((address_space(3))) unsigned int*)l, 16, 0, 0);
}

// ws layout: Cs f16[K][128] (hi only) | cnorm f32[K] | qcnt | qtok | kmin
#define CNORM_OFF  (KCODES * 256)
#define QCNT_OFF   (CNORM_OFF + KCODES * 4)
#define QTOK_OFF   (QCNT_OFF + 64)
#define KMIN_OFF   (QTOK_OFF + M_TOK * 4)

// -------------------------------------------------------------------------
// prep: exact fp32 cnorm + f16-hi codebook rows. Zeroes qcnt.
__global__ __launch_bounds__(256) void prep_kernel(
    const float* __restrict__ cb, unsigned short* __restrict__ Cs,
    float* __restrict__ cnorm, int* __restrict__ qcnt) {
  if (blockIdx.x == 0 && threadIdx.x == 0) *qcnt = 0;
  const int k = blockIdx.x * 4 + (threadIdx.x >> 6);
  const int lane = threadIdx.x & 63;
  const float2 v = ((const float2*)(cb + (size_t)k * DIM))[lane];
  float s = v.x * v.x + v.y * v.y;
  #pragma unroll
  for (int off = 32; off > 0; off >>= 1) s += __shfl_down(s, off);
  if (lane == 0) cnorm[k] = s;
  ushort2 hi;
  hi.x = f2h_bits((_Float16)v.x);
  hi.y = f2h_bits((_Float16)v.y);
  *(ushort2*)(Cs + (size_t)k * 128 + lane * 2) = hi;
}

// -------------------------------------------------------------------------
__global__ __launch_bounds__(256, 2) void vq_mfma_kernel(
    const float* __restrict__ ze, const unsigned short* __restrict__ Cs,
    const float* __restrict__ cnorm, const float* __restrict__ cb,
    int* __restrict__ qcnt, int* __restrict__ qtok,
    unsigned long long* __restrict__ kmin,
    float* __restrict__ out_zq, float* __restrict__ out_idx) {
  // Phase 1: As = lds[0:16K) (64 rows x 256 B, seg-XOR swizzled).
  // Phase 2: B staging ALIASES the full 64 KB (4 waves x 16 KB = 4 slice
  // bufs each, wave-private). A is dead after the ahi preload; the barrier
  // after the preload orders all waves' As reads before any DMA overwrite.
  __shared__ char lds[65536];
  char* const As = lds;

  const int tid = threadIdx.x;
  const int wn = tid >> 6;
  const int lane = tid & 63;
  const int quad = lane >> 4;
  const int l15 = lane & 15;
  const int m0 = blockIdx.x * BM;

  // Per-lane B-staging source offsets (verified mapping, hi-only rows:
  // 256 B stride). Dest slot s of local row r holds source seg s^((r>>1)&3).
  int loffC[4];
  #pragma unroll
  for (int c = 0; c < 4; ++c) {
    const int r = c * 16 + (lane >> 2);
    const int s = lane & 3;
    const int seg = s ^ ((r >> 1) & 3);
    loffC[c] = (wn * 64 + r) * 256 + seg * 16;
  }
  int boff[4];
  #pragma unroll
  for (int j = 0; j < 4; ++j) {
    const int n = j * 16 + l15;
    boff[j] = n * 64 + ((quad ^ ((n >> 1) & 3)) << 4);
  }
  char* const BsW = lds + wn * 16384;  // 4 slice bufs x 4096 B, wave-private

  // ---- stage As (hi only): fp32 -> f16, seg = (c>>3) ^ (r&7), 256 B rows --
  {
    const int r = tid >> 2;
    const int qh = tid & 3;
    const float* zrow = ze + (size_t)(m0 + r) * DIM + qh * 32;
    char* arow = As + r * 256;
    const int rx = r & 7;
    #pragma unroll
    for (int i = 0; i < 8; ++i) {
      const float4 v = *(const float4*)(zrow + i * 4);
      ushort4 hh;
      hh.x = f2h_bits((_Float16)v.x);
      hh.y = f2h_bits((_Float16)v.y);
      hh.z = f2h_bits((_Float16)v.z);
      hh.w = f2h_bits((_Float16)v.w);
      const int c = qh * 32 + i * 4;
      *(ushort4*)(arow + ((((c >> 3) ^ rx) << 4) | ((c & 7) << 1))) = hh;
    }
  }
  __syncthreads();

  // Preload all A-hi fragments into registers (reused for all 32 n-tiles).
  half8v ahi[4][4];
  #pragma unroll
  for (int ks = 0; ks < 4; ++ks)
    #pragma unroll
    for (int i = 0; i < 4; ++i) {
      const int m = i * 16 + l15;
      const int kslot = ks * 4 + quad;
      ahi[ks][i] = *(const half8v*)(As + m * 256 + ((kslot ^ (m & 7)) << 4));
    }
  __syncthreads();  // all waves' As reads done -> wave-private DMA may begin

  // Argmax of sc = x.c - cn/2 (equivalent to argmin of cn - 2 x.c).
  float bestv[16], secv[16], idxv[16];
  #pragma unroll
  for (int s = 0; s < 16; ++s) {
    bestv[s] = -3.4e38f; secv[s] = -3.4e38f; idxv[s] = 0.f;
  }

  for (int nt = 0; nt < NT; ++nt) {
    const char* const tile = (const char*)Cs + (size_t)nt * 65536;
    float cnv[4];
    #pragma unroll
    for (int j = 0; j < 4; ++j)
      cnv[j] = cnorm[nt * 256 + wn * 64 + j * 16 + l15];

    float4v acc[4][4];
    #pragma unroll
    for (int i = 0; i < 4; ++i)
      #pragma unroll
      for (int j = 0; j < 4; ++j) acc[i][j] = (float4v)0.0f;

    // Wave-private WAR: my ds_reads of the prior tile must complete before
    // my DMA overwrites the buffers. (Tile 0: covers the ahi preload too,
    // redundantly -- the barrier above already did block-wide.)
    asm volatile("s_waitcnt lgkmcnt(0)" ::: "memory");
    __builtin_amdgcn_sched_barrier(0);
    #pragma unroll
    for (int p = 0; p < 4; ++p)
      #pragma unroll
      for (int c = 0; c < 4; ++c)
        gload_lds16(tile + p * 64 + loffC[c], BsW + p * 4096 + c * 1024);
    // Wave-private RAW: my 16 loads landed -> my buffers are ready.
    asm volatile("s_waitcnt vmcnt(0)" ::: "memory");
    __builtin_amdgcn_sched_barrier(0);

    #pragma unroll
    for (int p = 0; p < 4; ++p) {
      half8v bf[4];
      #pragma unroll
      for (int j = 0; j < 4; ++j)
        bf[j] = *(const half8v*)(BsW + p * 4096 + boff[j]);
      #pragma unroll
      for (int i = 0; i < 4; ++i)
        #pragma unroll
        for (int j = 0; j < 4; ++j)
          acc[i][j] = __builtin_amdgcn_mfma_f32_16x16x32_f16(
              ahi[p][i], bf[j], acc[i][j], 0, 0, 0);
    }

    // Fold screen scores (argmax; R4-verified form). Ascending n, strict >
    // keeps lowest index on ties. sec' = med3(sc, best, sec) is exactly the
    // new runner-up; cnorm folded via fmaf AFTER the MFMA chain.
    #pragma unroll
    for (int j = 0; j < 4; ++j) {
      const float nidx = (float)(nt * 256 + wn * 64 + j * 16 + l15);
      const float cn = cnv[j];
      #pragma unroll
      for (int i = 0; i < 4; ++i)
        #pragma unroll
        for (int rg = 0; rg < 4; ++rg) {
          const float sc = fmaf(-0.5f, cn, acc[i][j][rg]);
          const int slot = i * 4 + rg;
          const bool bt = sc > bestv[slot];
          secv[slot] = __builtin_amdgcn_fmed3f(sc, bestv[slot], secv[slot]);
          idxv[slot] = bt ? nidx : idxv[slot];
          bestv[slot] = fmaxf(bestv[slot], sc);
        }
    }
  }

  // Cross-lane reduce (16 lanes per token row, tie -> lowest index).
  #pragma unroll
  for (int slot = 0; slot < 16; ++slot) {
    float b = bestv[slot], sec = secv[slot], ix = idxv[slot];
    #pragma unroll
    for (int mk = 1; mk <= 8; mk <<= 1) {
      const float ob = __shfl_xor(b, mk);
      const float os = __shfl_xor(sec, mk);
      const float oi = __shfl_xor(ix, mk);
      const bool take = (ob > b) || (ob == b && oi < ix);
      const float loser = take ? b : ob;
      b = take ? ob : b;
      ix = take ? oi : ix;
      sec = fmaxf(fmaxf(sec, os), loser);
    }
    bestv[slot] = b; secv[slot] = sec; idxv[slot] = ix;
  }

  // Cross-wave merge via LDS. Each wave drained its own DMA (vmcnt(0)
  // above), so after this barrier the lds region is safe to reuse.
  __syncthreads();
  float* const redB = (float*)lds;
  float* const redS = redB + 256;
  float* const redI = redB + 512;
  float* const lidxs = redB + 768;
  if (l15 == 0) {
    #pragma unroll
    for (int slot = 0; slot < 16; ++slot) {
      const int row = (slot >> 2) * 16 + quad * 4 + (slot & 3);
      redB[wn * 64 + row] = bestv[slot];
      redS[wn * 64 + row] = secv[slot];
      redI[wn * 64 + row] = idxv[slot];
    }
  }
  __syncthreads();
  if (tid < 64) {
    float b = redB[tid], sec = redS[tid], ix = redI[tid];
    #pragma unroll
    for (int w = 1; w < 4; ++w) {
      const float ob = redB[w * 64 + tid];
      const float os = redS[w * 64 + tid];
      const float oi = redI[w * 64 + tid];
      const bool take = (ob > b) || (ob == b && oi < ix);
      const float loser = take ? b : ob;
      b = take ? ob : b;
      ix = take ? oi : ix;
      sec = fmaxf(fmaxf(sec, os), loser);
    }
    out_idx[m0 + tid] = ix;
    lidxs[tid] = ix;
    // acc-domain gap: d2-gap = 2*(b - sec)  =>  test (b-sec) < MARGIN/2.
    if (b - sec < 0.5f * MARGIN) {  // ambiguous under screen error -> rescan
      kmin[m0 + tid] = ~0ull;
      const int p = atomicAdd(qcnt, 1);
      qtok[p] = m0 + tid;
    }
  }
  __syncthreads();

  // Provisional z_q gather for this block's 64 tokens.
  const int tl = tid >> 2, qp = tid & 3;
  const int code = (int)lidxs[tl];
  const float4* src = (const float4*)(cb + (size_t)code * DIM);
  float4* dst = (float4*)(out_zq + (size_t)(m0 + tl) * DIM);
  #pragma unroll
  for (int p = 0; p < 8; ++p) dst[qp + p * 4] = src[qp + p * 4];
}

// -------------------------------------------------------------------------
// Parallel exact rescan v2 (R8-verified). Block b: code-group (b&7)*1024,
// token group (b>>3): RTG tokens staged in LDS, 4 codes/thread.
__global__ __launch_bounds__(256) void rescan_part_kernel(
    const float* __restrict__ ze, const float* __restrict__ cb,
    const float* __restrict__ cnorm, const int* __restrict__ qcnt,
    const int* __restrict__ qtok, unsigned long long* __restrict__ kmin) {
  __shared__ float xsh[RTG][132];                 // padded: bank-spread
  __shared__ unsigned long long wpart[4][RTG];
  const int tid = threadIdx.x;
  const int wv = tid >> 6;
  const int lane = tid & 63;
  const int cg = blockIdx.x & 7;                  // code group (1024 codes)
  const int n = *qcnt;
  const int nslots = gridDim.x >> 3;
  const int c0 = cg * 1024 + tid;                 // codes c0 + k*256, k=0..3

  for (int g = blockIdx.x >> 3; g * RTG < n; g += nslots) {
    const int cnt = min(RTG, n - g * RTG);
    __syncthreads();                              // xsh/wpart safe to reuse
    if ((tid >> 5) < cnt) {                       // 8 tokens x 32 float4
      const int token = qtok[g * RTG + (tid >> 5)];
      const float4 v =
          ((const float4*)(ze + (size_t)token * DIM))[tid & 31];
      ((float4*)(xsh[tid >> 5]))[tid & 31] = v;
    }
    __syncthreads();

    float dot[4][RTG];
    #pragma unroll
    for (int k = 0; k < 4; ++k)
      #pragma unroll
      for (int t = 0; t < RTG; ++t) dot[k][t] = 0.f;

    const float* crow0 = cb + (size_t)c0 * DIM;
    for (int d = 0; d < DIM; d += 4) {
      float4 x4[RTG];
      #pragma unroll
      for (int t = 0; t < RTG; ++t)
        x4[t] = *(const float4*)(xsh[t] + d);     // wave-uniform broadcast
      #pragma unroll
      for (int k = 0; k < 4; ++k) {
        const float4 c4 = *(const float4*)(crow0 + (size_t)k * 256 * DIM + d);
        #pragma unroll
        for (int t = 0; t < RTG; ++t) {
          dot[k][t] = fmaf(c4.x, x4[t].x, dot[k][t]);
          dot[k][t] = fmaf(c4.y, x4[t].y, dot[k][t]);
          dot[k][t] = fmaf(c4.z, x4[t].z, dot[k][t]);
          dot[k][t] = fmaf(c4.w, x4[t].w, dot[k][t]);
        }
      }
    }

    float cn[4];
    #pragma unroll
    for (int k = 0; k < 4; ++k) cn[k] = cnorm[c0 + k * 256];

    #pragma unroll
    for (int t = 0; t < RTG; ++t) {
      float s = fmaf(-2.f, dot[0][t], cn[0]);
      int ix = c0;
      #pragma unroll
      for (int k = 1; k < 4; ++k) {
        const float sk = fmaf(-2.f, dot[k][t], cn[k]);
        if (sk < s) { s = sk; ix = c0 + k * 256; }
      }
      #pragma unroll
      for (int mk = 1; mk <= 32; mk <<= 1) {
        const float os = __shfl_xor(s, mk);
        const int oi = __shfl_xor(ix, mk);
        if (os < s || (os == s && oi < ix)) { s = os; ix = oi; }
      }
      if (lane == 0) {
        union { float f; unsigned u; } c; c.f = s;
        const unsigned m = (c.u >> 31) ? ~c.u : (c.u | 0x80000000u);
        wpart[wv][t] = ((unsigned long long)m << 32) | (unsigned)ix;
      }
    }
    __syncthreads();
    if (tid < cnt) {
      unsigned long long k = wpart[0][tid];
      #pragma unroll
      for (int w = 1; w < 4; ++w) k = min(k, wpart[w][tid]);
      atomicMin(&kmin[qtok[g * RTG + tid]], k);
    }
  }
}

// -------------------------------------------------------------------------
// Apply rescan results: decode keys, rewrite idx + z_q rows.
__global__ __launch_bounds__(256) void rescan_apply_kernel(
    const float* __restrict__ cb, const int* __restrict__ qcnt,
    const int* __restrict__ qtok, const unsigned long long* __restrict__ kmin,
    float* __restrict__ out_zq, float* __restrict__ out_idx) {
  const int tid = threadIdx.x;
  const int n = *qcnt;
  for (int qi = blockIdx.x; qi < n; qi += gridDim.x) {
    const int token = qtok[qi];
    const int code = (int)(unsigned int)(kmin[token] & 0xFFFFFFFFull);
    if (tid == 0) out_idx[token] = (float)code;
    if (tid < 32)
      ((float4*)(out_zq + (size_t)token * DIM))[tid] =
          ((const float4*)(cb + (size_t)code * DIM))[tid];
  }
}

// -------------------------------------------------------------------------
extern "C" void kernel_launch(void* const* d_in, const int* in_sizes, int n_in,
                              void* d_out, int out_size, void* d_ws,
                              size_t ws_size, hipStream_t stream) {
  const float* ze = (const float*)d_in[0];
  const float* cb = (const float*)d_in[1];
  float* out = (float*)d_out;

  unsigned short* Cs = (unsigned short*)d_ws;
  float* cnorm = (float*)((char*)d_ws + CNORM_OFF);
  int* qcnt = (int*)((char*)d_ws + QCNT_OFF);
  int* qtok = (int*)((char*)d_ws + QTOK_OFF);
  unsigned long long* kmin = (unsigned long long*)((char*)d_ws + KMIN_OFF);

  prep_kernel<<<KCODES / 4, 256, 0, stream>>>(cb, Cs, cnorm, qcnt);
  vq_mfma_kernel<<<M_TOK / BM, 256, 0, stream>>>(
      ze, Cs, cnorm, cb, qcnt, qtok, kmin, out, out + (size_t)M_TOK * DIM);
  rescan_part_kernel<<<4096, 256, 0, stream>>>(ze, cb, cnorm, qcnt, qtok,
                                               kmin);
  rescan_apply_kernel<<<256, 256, 0, stream>>>(cb, qcnt, qtok, kmin, out,
                                               out + (size_t)M_TOK * DIM);
}

// Round 16
// 250.453 us; speedup vs baseline: 1.0358x; 1.0358x over previous
//
#include <hip/hip_runtime.h>

// VQ argmin: 1-pass f16 SCREEN on matrix cores (xh.ch only, score error
// sigma ~9e-3) + exact fp32 parallel rescan for tokens whose screen
// best2-best1 gap < MARGIN (expected ~1.5% of tokens).
// R15 (on R14, vq=110.5us): INTRA-TILE COUNTED vmcnt. R14 drained all 16
// DMA loads (vmcnt(0)) before consuming slice 0 -- full latency+transfer
// exposed per tile. Now slice p waits vmcnt(12/8/4/0): slices 1-3 transfer
// hides under slices 0-2 MFMA. Counts are safe because (a) the WAR fence
// (lgkmcnt(0)+sched_barrier before all stages) is unchanged from verified
// R14, (b) the only other VMEM op in the window (cnv load) is pinned BEFORE
// the fence in source order, is the oldest outstanding op, and in-order
// vmcnt retirement makes vmcnt(12) => {cnv, slice0} retired. (R3's race:
// cnv issued BETWEEN stage groups corrupted its counted waits + no
// sched_barrier per rule 18 -- both fixed here.)
// Everything else byte-identical to R14.

#define M_TOK  32768
#define DIM    128
#define KCODES 8192
#define BM     64
#define NT     (KCODES / 256)   // 32 n-tiles per block
#define MARGIN 0.10f            // ~8 sigma of screen pair error; gap scale 6.9
#define RTG    8                // tokens per rescan group

typedef _Float16 half8v __attribute__((ext_vector_type(8)));
typedef float float4v __attribute__((ext_vector_type(4)));

union H2U { _Float16 h; unsigned short u; };
__device__ __forceinline__ unsigned short f2h_bits(_Float16 h) {
  H2U c; c.h = h; return c.u;
}

__device__ __forceinline__ void gload_lds16(const void* g, void* l) {
  __builtin_amdgcn_global_load_lds(
      (const __attribute__((address_space(1))) unsigned int*)g,
      (__attribute__((address_space(3))) unsigned int*)l, 16, 0, 0);
}

// Consume slice P after a counted wait: slice P's 4 loads retired when
// outstanding <= (3-P)*4 (cnv is oldest, retires first; conservative-safe).
#define CONSUME_SLICE(P, CNTTXT)                                       \
  do {                                                                 \
    asm volatile("s_waitcnt vmcnt(" CNTTXT ")" ::: "memory");          \
    __builtin_amdgcn_sched_barrier(0);                                 \
    half8v bf[4];                                                      \
    _Pragma("unroll") for (int j_ = 0; j_ < 4; ++j_)                   \
      bf[j_] = *(const half8v*)(BsW + (P) * 4096 + boff[j_]);          \
    _Pragma("unroll") for (int i_ = 0; i_ < 4; ++i_)                   \
      _Pragma("unroll") for (int j_ = 0; j_ < 4; ++j_)                 \
        acc[i_][j_] = __builtin_amdgcn_mfma_f32_16x16x32_f16(          \
            ahi[P][i_], bf[j_], acc[i_][j_], 0, 0, 0);                 \
  } while (0)

// ws layout: Cs f16[K][128] (hi only) | cnorm f32[K] | qcnt | qtok | kmin
#define CNORM_OFF  (KCODES * 256)
#define QCNT_OFF   (CNORM_OFF + KCODES * 4)
#define QTOK_OFF   (QCNT_OFF + 64)
#define KMIN_OFF   (QTOK_OFF + M_TOK * 4)

// -------------------------------------------------------------------------
// prep: exact fp32 cnorm + f16-hi codebook rows. Zeroes qcnt.
__global__ __launch_bounds__(256) void prep_kernel(
    const float* __restrict__ cb, unsigned short* __restrict__ Cs,
    float* __restrict__ cnorm, int* __restrict__ qcnt) {
  if (blockIdx.x == 0 && threadIdx.x == 0) *qcnt = 0;
  const int k = blockIdx.x * 4 + (threadIdx.x >> 6);
  const int lane = threadIdx.x & 63;
  const float2 v = ((const float2*)(cb + (size_t)k * DIM))[lane];
  float s = v.x * v.x + v.y * v.y;
  #pragma unroll
  for (int off = 32; off > 0; off >>= 1) s += __shfl_down(s, off);
  if (lane == 0) cnorm[k] = s;
  ushort2 hi;
  hi.x = f2h_bits((_Float16)v.x);
  hi.y = f2h_bits((_Float16)v.y);
  *(ushort2*)(Cs + (size_t)k * 128 + lane * 2) = hi;
}

// -------------------------------------------------------------------------
__global__ __launch_bounds__(256, 2) void vq_mfma_kernel(
    const float* __restrict__ ze, const unsigned short* __restrict__ Cs,
    const float* __restrict__ cnorm, const float* __restrict__ cb,
    int* __restrict__ qcnt, int* __restrict__ qtok,
    unsigned long long* __restrict__ kmin,
    float* __restrict__ out_zq, float* __restrict__ out_idx) {
  // Phase 1: As = lds[0:16K) (64 rows x 256 B, seg-XOR swizzled).
  // Phase 2: B staging ALIASES the full 64 KB (4 waves x 16 KB = 4 slice
  // bufs each, wave-private). A is dead after the ahi preload; the barrier
  // after the preload orders all waves' As reads before any DMA overwrite.
  __shared__ char lds[65536];
  char* const As = lds;

  const int tid = threadIdx.x;
  const int wn = tid >> 6;
  const int lane = tid & 63;
  const int quad = lane >> 4;
  const int l15 = lane & 15;
  const int m0 = blockIdx.x * BM;

  // Per-lane B-staging source offsets (verified mapping, hi-only rows:
  // 256 B stride). Dest slot s of local row r holds source seg s^((r>>1)&3).
  int loffC[4];
  #pragma unroll
  for (int c = 0; c < 4; ++c) {
    const int r = c * 16 + (lane >> 2);
    const int s = lane & 3;
    const int seg = s ^ ((r >> 1) & 3);
    loffC[c] = (wn * 64 + r) * 256 + seg * 16;
  }
  int boff[4];
  #pragma unroll
  for (int j = 0; j < 4; ++j) {
    const int n = j * 16 + l15;
    boff[j] = n * 64 + ((quad ^ ((n >> 1) & 3)) << 4);
  }
  char* const BsW = lds + wn * 16384;  // 4 slice bufs x 4096 B, wave-private

  // ---- stage As (hi only): fp32 -> f16, seg = (c>>3) ^ (r&7), 256 B rows --
  {
    const int r = tid >> 2;
    const int qh = tid & 3;
    const float* zrow = ze + (size_t)(m0 + r) * DIM + qh * 32;
    char* arow = As + r * 256;
    const int rx = r & 7;
    #pragma unroll
    for (int i = 0; i < 8; ++i) {
      const float4 v = *(const float4*)(zrow + i * 4);
      ushort4 hh;
      hh.x = f2h_bits((_Float16)v.x);
      hh.y = f2h_bits((_Float16)v.y);
      hh.z = f2h_bits((_Float16)v.z);
      hh.w = f2h_bits((_Float16)v.w);
      const int c = qh * 32 + i * 4;
      *(ushort4*)(arow + ((((c >> 3) ^ rx) << 4) | ((c & 7) << 1))) = hh;
    }
  }
  __syncthreads();

  // Preload all A-hi fragments into registers (reused for all 32 n-tiles).
  half8v ahi[4][4];
  #pragma unroll
  for (int ks = 0; ks < 4; ++ks)
    #pragma unroll
    for (int i = 0; i < 4; ++i) {
      const int m = i * 16 + l15;
      const int kslot = ks * 4 + quad;
      ahi[ks][i] = *(const half8v*)(As + m * 256 + ((kslot ^ (m & 7)) << 4));
    }
  __syncthreads();  // all waves' As reads done -> wave-private DMA may begin

  // Argmax of sc = x.c - cn/2 (equivalent to argmin of cn - 2 x.c).
  float bestv[16], secv[16], idxv[16];
  #pragma unroll
  for (int s = 0; s < 16; ++s) {
    bestv[s] = -3.4e38f; secv[s] = -3.4e38f; idxv[s] = 0.f;
  }

  for (int nt = 0; nt < NT; ++nt) {
    const char* const tile = (const char*)Cs + (size_t)nt * 65536;
    // cnv load pinned BEFORE the fence below (oldest outstanding VMEM op;
    // retires first, keeping the counted waits conservative-correct).
    float cnv[4];
    #pragma unroll
    for (int j = 0; j < 4; ++j)
      cnv[j] = cnorm[nt * 256 + wn * 64 + j * 16 + l15];

    float4v acc[4][4];
    #pragma unroll
    for (int i = 0; i < 4; ++i)
      #pragma unroll
      for (int j = 0; j < 4; ++j) acc[i][j] = (float4v)0.0f;

    // Wave-private WAR: my ds_reads of the prior tile must complete before
    // my DMA overwrites the buffers (unchanged from verified R14).
    asm volatile("s_waitcnt lgkmcnt(0)" ::: "memory");
    __builtin_amdgcn_sched_barrier(0);
    #pragma unroll
    for (int p = 0; p < 4; ++p)
      #pragma unroll
      for (int c = 0; c < 4; ++c)
        gload_lds16(tile + p * 64 + loffC[c], BsW + p * 4096 + c * 1024);

    // Counted RAW waits: consume slice p once its 4 loads retired, while
    // slices p+1..3 are still in flight (transfer hides under MFMA).
    CONSUME_SLICE(0, "12");
    CONSUME_SLICE(1, "8");
    CONSUME_SLICE(2, "4");
    CONSUME_SLICE(3, "0");

    // Fold screen scores (argmax; R4-verified form). Ascending n, strict >
    // keeps lowest index on ties. sec' = med3(sc, best, sec) is exactly the
    // new runner-up; cnorm folded via fmaf AFTER the MFMA chain.
    #pragma unroll
    for (int j = 0; j < 4; ++j) {
      const float nidx = (float)(nt * 256 + wn * 64 + j * 16 + l15);
      const float cn = cnv[j];
      #pragma unroll
      for (int i = 0; i < 4; ++i)
        #pragma unroll
        for (int rg = 0; rg < 4; ++rg) {
          const float sc = fmaf(-0.5f, cn, acc[i][j][rg]);
          const int slot = i * 4 + rg;
          const bool bt = sc > bestv[slot];
          secv[slot] = __builtin_amdgcn_fmed3f(sc, bestv[slot], secv[slot]);
          idxv[slot] = bt ? nidx : idxv[slot];
          bestv[slot] = fmaxf(bestv[slot], sc);
        }
    }
  }

  // Cross-lane reduce (16 lanes per token row, tie -> lowest index).
  #pragma unroll
  for (int slot = 0; slot < 16; ++slot) {
    float b = bestv[slot], sec = secv[slot], ix = idxv[slot];
    #pragma unroll
    for (int mk = 1; mk <= 8; mk <<= 1) {
      const float ob = __shfl_xor(b, mk);
      const float os = __shfl_xor(sec, mk);
      const float oi = __shfl_xor(ix, mk);
      const bool take = (ob > b) || (ob == b && oi < ix);
      const float loser = take ? b : ob;
      b = take ? ob : b;
      ix = take ? oi : ix;
      sec = fmaxf(fmaxf(sec, os), loser);
    }
    bestv[slot] = b; secv[slot] = sec; idxv[slot] = ix;
  }

  // Cross-wave merge via LDS. Each wave drained its own DMA (vmcnt(0) at
  // slice 3), so after this barrier the lds region is safe to reuse.
  __syncthreads();
  float* const redB = (float*)lds;
  float* const redS = redB + 256;
  float* const redI = redB + 512;
  float* const lidxs = redB + 768;
  if (l15 == 0) {
    #pragma unroll
    for (int slot = 0; slot < 16; ++slot) {
      const int row = (slot >> 2) * 16 + quad * 4 + (slot & 3);
      redB[wn * 64 + row] = bestv[slot];
      redS[wn * 64 + row] = secv[slot];
      redI[wn * 64 + row] = idxv[slot];
    }
  }
  __syncthreads();
  if (tid < 64) {
    float b = redB[tid], sec = redS[tid], ix = redI[tid];
    #pragma unroll
    for (int w = 1; w < 4; ++w) {
      const float ob = redB[w * 64 + tid];
      const float os = redS[w * 64 + tid];
      const float oi = redI[w * 64 + tid];
      const bool take = (ob > b) || (ob == b && oi < ix);
      const float loser = take ? b : ob;
      b = take ? ob : b;
      ix = take ? oi : ix;
      sec = fmaxf(fmaxf(sec, os), loser);
    }
    out_idx[m0 + tid] = ix;
    lidxs[tid] = ix;
    // acc-domain gap: d2-gap = 2*(b - sec)  =>  test (b-sec) < MARGIN/2.
    if (b - sec < 0.5f * MARGIN) {  // ambiguous under screen error -> rescan
      kmin[m0 + tid] = ~0ull;
      const int p = atomicAdd(qcnt, 1);
      qtok[p] = m0 + tid;
    }
  }
  __syncthreads();

  // Provisional z_q gather for this block's 64 tokens.
  const int tl = tid >> 2, qp = tid & 3;
  const int code = (int)lidxs[tl];
  const float4* src = (const float4*)(cb + (size_t)code * DIM);
  float4* dst = (float4*)(out_zq + (size_t)(m0 + tl) * DIM);
  #pragma unroll
  for (int p = 0; p < 8; ++p) dst[qp + p * 4] = src[qp + p * 4];
}

// -------------------------------------------------------------------------
// Parallel exact rescan v2 (R8-verified). Block b: code-group (b&7)*1024,
// token group (b>>3): RTG tokens staged in LDS, 4 codes/thread.
__global__ __launch_bounds__(256) void rescan_part_kernel(
    const float* __restrict__ ze, const float* __restrict__ cb,
    const float* __restrict__ cnorm, const int* __restrict__ qcnt,
    const int* __restrict__ qtok, unsigned long long* __restrict__ kmin) {
  __shared__ float xsh[RTG][132];                 // padded: bank-spread
  __shared__ unsigned long long wpart[4][RTG];
  const int tid = threadIdx.x;
  const int wv = tid >> 6;
  const int lane = tid & 63;
  const int cg = blockIdx.x & 7;                  // code group (1024 codes)
  const int n = *qcnt;
  const int nslots = gridDim.x >> 3;
  const int c0 = cg * 1024 + tid;                 // codes c0 + k*256, k=0..3

  for (int g = blockIdx.x >> 3; g * RTG < n; g += nslots) {
    const int cnt = min(RTG, n - g * RTG);
    __syncthreads();                              // xsh/wpart safe to reuse
    if ((tid >> 5) < cnt) {                       // 8 tokens x 32 float4
      const int token = qtok[g * RTG + (tid >> 5)];
      const float4 v =
          ((const float4*)(ze + (size_t)token * DIM))[tid & 31];
      ((float4*)(xsh[tid >> 5]))[tid & 31] = v;
    }
    __syncthreads();

    float dot[4][RTG];
    #pragma unroll
    for (int k = 0; k < 4; ++k)
      #pragma unroll
      for (int t = 0; t < RTG; ++t) dot[k][t] = 0.f;

    const float* crow0 = cb + (size_t)c0 * DIM;
    for (int d = 0; d < DIM; d += 4) {
      float4 x4[RTG];
      #pragma unroll
      for (int t = 0; t < RTG; ++t)
        x4[t] = *(const float4*)(xsh[t] + d);     // wave-uniform broadcast
      #pragma unroll
      for (int k = 0; k < 4; ++k) {
        const float4 c4 = *(const float4*)(crow0 + (size_t)k * 256 * DIM + d);
        #pragma unroll
        for (int t = 0; t < RTG; ++t) {
          dot[k][t] = fmaf(c4.x, x4[t].x, dot[k][t]);
          dot[k][t] = fmaf(c4.y, x4[t].y, dot[k][t]);
          dot[k][t] = fmaf(c4.z, x4[t].z, dot[k][t]);
          dot[k][t] = fmaf(c4.w, x4[t].w, dot[k][t]);
        }
      }
    }

    float cn[4];
    #pragma unroll
    for (int k = 0; k < 4; ++k) cn[k] = cnorm[c0 + k * 256];

    #pragma unroll
    for (int t = 0; t < RTG; ++t) {
      float s = fmaf(-2.f, dot[0][t], cn[0]);
      int ix = c0;
      #pragma unroll
      for (int k = 1; k < 4; ++k) {
        const float sk = fmaf(-2.f, dot[k][t], cn[k]);
        if (sk < s) { s = sk; ix = c0 + k * 256; }
      }
      #pragma unroll
      for (int mk = 1; mk <= 32; mk <<= 1) {
        const float os = __shfl_xor(s, mk);
        const int oi = __shfl_xor(ix, mk);
        if (os < s || (os == s && oi < ix)) { s = os; ix = oi; }
      }
      if (lane == 0) {
        union { float f; unsigned u; } c; c.f = s;
        const unsigned m = (c.u >> 31) ? ~c.u : (c.u | 0x80000000u);
        wpart[wv][t] = ((unsigned long long)m << 32) | (unsigned)ix;
      }
    }
    __syncthreads();
    if (tid < cnt) {
      unsigned long long k = wpart[0][tid];
      #pragma unroll
      for (int w = 1; w < 4; ++w) k = min(k, wpart[w][tid]);
      atomicMin(&kmin[qtok[g * RTG + tid]], k);
    }
  }
}

// -------------------------------------------------------------------------
// Apply rescan results: decode keys, rewrite idx + z_q rows.
__global__ __launch_bounds__(256) void rescan_apply_kernel(
    const float* __restrict__ cb, const int* __restrict__ qcnt,
    const int* __restrict__ qtok, const unsigned long long* __restrict__ kmin,
    float* __restrict__ out_zq, float* __restrict__ out_idx) {
  const int tid = threadIdx.x;
  const int n = *qcnt;
  for (int qi = blockIdx.x; qi < n; qi += gridDim.x) {
    const int token = qtok[qi];
    const int code = (int)(unsigned int)(kmin[token] & 0xFFFFFFFFull);
    if (tid == 0) out_idx[token] = (float)code;
    if (tid < 32)
      ((float4*)(out_zq + (size_t)token * DIM))[tid] =
          ((const float4*)(cb + (size_t)code * DIM))[tid];
  }
}

// -------------------------------------------------------------------------
extern "C" void kernel_launch(void* const* d_in, const int* in_sizes, int n_in,
                              void* d_out, int out_size, void* d_ws,
                              size_t ws_size, hipStream_t stream) {
  const float* ze = (const float*)d_in[0];
  const float* cb = (const float*)d_in[1];
  float* out = (float*)d_out;

  unsigned short* Cs = (unsigned short*)d_ws;
  float* cnorm = (float*)((char*)d_ws + CNORM_OFF);
  int* qcnt = (int*)((char*)d_ws + QCNT_OFF);
  int* qtok = (int*)((char*)d_ws + QTOK_OFF);
  unsigned long long* kmin = (unsigned long long*)((char*)d_ws + KMIN_OFF);

  prep_kernel<<<KCODES / 4, 256, 0, stream>>>(cb, Cs, cnorm, qcnt);
  vq_mfma_kernel<<<M_TOK / BM, 256, 0, stream>>>(
      ze, Cs, cnorm, cb, qcnt, qtok, kmin, out, out + (size_t)M_TOK * DIM);
  rescan_part_kernel<<<4096, 256, 0, stream>>>(ze, cb, cnorm, qcnt, qtok,
                                               kmin);
  rescan_apply_kernel<<<256, 256, 0, stream>>>(cb, qcnt, qtok, kmin, out,
                                               out + (size_t)M_TOK * DIM);
}

// Round 17
// 248.785 us; speedup vs baseline: 1.0428x; 1.0067x over previous
//
#include <hip/hip_runtime.h>

// VQ argmin: 1-pass f16 SCREEN on matrix cores (xh.ch only, score error
// sigma ~9e-3) + exact fp32 parallel rescan for tokens whose screen
// best2-best1 gap < MARGIN (expected ~1.5% of tokens).
// R16 (on R15, vq=107.6us): DEPTH-1 CROSS-TILE PREFETCH with deterministic
// counted vmcnt. Fixed per-iteration VMEM issue order (in-order retire):
// loop top = [cnv(nt)4, S0..S3(nt)16] (20 outstanding). C0 waits vm12
// (retires cnv+S0), C1 vm8; then issue [cnv(nt+1)4, S0'S1'8] into freed
// bufs 0,1 (WAR: their ds_reads are register-complete before the MFMAs,
// sched_barrier pins order); C2 waits vm16 (S2 now oldest), C3 vm12; then
// issue [S2'S3'8] -> loop top back to 20. Last tile peeled (12/8/4/0
// epilogue) so no branch perturbs the counts. R3's races (cnv issued
// mid-stream breaking counts; no sched_barrier) are structurally excluded.
// Everything else byte-identical to R15.

#define M_TOK  32768
#define DIM    128
#define KCODES 8192
#define BM     64
#define NT     (KCODES / 256)   // 32 n-tiles per block
#define MARGIN 0.10f            // ~8 sigma of screen pair error; gap scale 6.9
#define RTG    8                // tokens per rescan group

typedef _Float16 half8v __attribute__((ext_vector_type(8)));
typedef float float4v __attribute__((ext_vector_type(4)));

union H2U { _Float16 h; unsigned short u; };
__device__ __forceinline__ unsigned short f2h_bits(_Float16 h) {
  H2U c; c.h = h; return c.u;
}

__device__ __forceinline__ void gload_lds16(const void* g, void* l) {
  __builtin_amdgcn_global_load_lds(
      (const __attribute__((address_space(1))) unsigned int*)g,
      (__attribute__((address_space(3))) unsigned int*)l, 16, 0, 0);
}

// Consume slice P after a counted wait (CNTTXT = literal count text).
#define CONSUME_SLICE(P, CNTTXT)                                       \
  do {                                                                 \
    asm volatile("s_waitcnt vmcnt(" CNTTXT ")" ::: "memory");          \
    __builtin_amdgcn_sched_barrier(0);                                 \
    half8v bf[4];                                                      \
    _Pragma("unroll") for (int j_ = 0; j_ < 4; ++j_)                   \
      bf[j_] = *(const half8v*)(BsW + (P) * 4096 + boff[j_]);          \
    _Pragma("unroll") for (int i_ = 0; i_ < 4; ++i_)                   \
      _Pragma("unroll") for (int j_ = 0; j_ < 4; ++j_)                 \
        acc[i_][j_] = __builtin_amdgcn_mfma_f32_16x16x32_f16(          \
            ahi[P][i_], bf[j_], acc[i_][j_], 0, 0, 0);                 \
  } while (0)

// Stage one 64B k-slice (4 loads) of tile base TB into buffer P.
#define STAGE_SLICE(TB, P)                                             \
  do {                                                                 \
    _Pragma("unroll") for (int c_ = 0; c_ < 4; ++c_)                   \
      gload_lds16((TB) + (P) * 64 + loffC[c_],                         \
                  BsW + (P) * 4096 + c_ * 1024);                       \
  } while (0)

// Fold 64 screen scores for the tile whose cnorm regs are CNV (argmax;
// sc = acc - cn/2; med3 runner-up; strict > keeps lowest index on ties).
#define FOLD_TILE(NTV, CNV)                                            \
  do {                                                                 \
    _Pragma("unroll") for (int j_ = 0; j_ < 4; ++j_) {                 \
      const float nidx_ =                                              \
          (float)((NTV) * 256 + wn * 64 + j_ * 16 + l15);              \
      const float cn_ = (CNV)[j_];                                     \
      _Pragma("unroll") for (int i_ = 0; i_ < 4; ++i_)                 \
        _Pragma("unroll") for (int rg_ = 0; rg_ < 4; ++rg_) {          \
          const float sc_ = fmaf(-0.5f, cn_, acc[i_][j_][rg_]);        \
          const int slot_ = i_ * 4 + rg_;                              \
          const bool bt_ = sc_ > bestv[slot_];                         \
          secv[slot_] =                                                \
              __builtin_amdgcn_fmed3f(sc_, bestv[slot_], secv[slot_]); \
          idxv[slot_] = bt_ ? nidx_ : idxv[slot_];                     \
          bestv[slot_] = fmaxf(bestv[slot_], sc_);                     \
        }                                                              \
    }                                                                  \
  } while (0)

// ws layout: Cs f16[K][128] (hi only) | cnorm f32[K] | qcnt | qtok | kmin
#define CNORM_OFF  (KCODES * 256)
#define QCNT_OFF   (CNORM_OFF + KCODES * 4)
#define QTOK_OFF   (QCNT_OFF + 64)
#define KMIN_OFF   (QTOK_OFF + M_TOK * 4)

// -------------------------------------------------------------------------
// prep: exact fp32 cnorm + f16-hi codebook rows. Zeroes qcnt.
__global__ __launch_bounds__(256) void prep_kernel(
    const float* __restrict__ cb, unsigned short* __restrict__ Cs,
    float* __restrict__ cnorm, int* __restrict__ qcnt) {
  if (blockIdx.x == 0 && threadIdx.x == 0) *qcnt = 0;
  const int k = blockIdx.x * 4 + (threadIdx.x >> 6);
  const int lane = threadIdx.x & 63;
  const float2 v = ((const float2*)(cb + (size_t)k * DIM))[lane];
  float s = v.x * v.x + v.y * v.y;
  #pragma unroll
  for (int off = 32; off > 0; off >>= 1) s += __shfl_down(s, off);
  if (lane == 0) cnorm[k] = s;
  ushort2 hi;
  hi.x = f2h_bits((_Float16)v.x);
  hi.y = f2h_bits((_Float16)v.y);
  *(ushort2*)(Cs + (size_t)k * 128 + lane * 2) = hi;
}

// -------------------------------------------------------------------------
__global__ __launch_bounds__(256, 2) void vq_mfma_kernel(
    const float* __restrict__ ze, const unsigned short* __restrict__ Cs,
    const float* __restrict__ cnorm, const float* __restrict__ cb,
    int* __restrict__ qcnt, int* __restrict__ qtok,
    unsigned long long* __restrict__ kmin,
    float* __restrict__ out_zq, float* __restrict__ out_idx) {
  // Phase 1: As = lds[0:16K) (64 rows x 256 B, seg-XOR swizzled).
  // Phase 2: B staging ALIASES the full 64 KB (4 waves x 16 KB = 4 slice
  // bufs each, wave-private). A is dead after the ahi preload; the barrier
  // after the preload orders all waves' As reads before any DMA overwrite.
  __shared__ char lds[65536];
  char* const As = lds;

  const int tid = threadIdx.x;
  const int wn = tid >> 6;
  const int lane = tid & 63;
  const int quad = lane >> 4;
  const int l15 = lane & 15;
  const int m0 = blockIdx.x * BM;

  // Per-lane B-staging source offsets (verified mapping, hi-only rows:
  // 256 B stride). Dest slot s of local row r holds source seg s^((r>>1)&3).
  int loffC[4];
  #pragma unroll
  for (int c = 0; c < 4; ++c) {
    const int r = c * 16 + (lane >> 2);
    const int s = lane & 3;
    const int seg = s ^ ((r >> 1) & 3);
    loffC[c] = (wn * 64 + r) * 256 + seg * 16;
  }
  int boff[4];
  #pragma unroll
  for (int j = 0; j < 4; ++j) {
    const int n = j * 16 + l15;
    boff[j] = n * 64 + ((quad ^ ((n >> 1) & 3)) << 4);
  }
  char* const BsW = lds + wn * 16384;  // 4 slice bufs x 4096 B, wave-private

  // ---- stage As (hi only): fp32 -> f16, seg = (c>>3) ^ (r&7), 256 B rows --
  {
    const int r = tid >> 2;
    const int qh = tid & 3;
    const float* zrow = ze + (size_t)(m0 + r) * DIM + qh * 32;
    char* arow = As + r * 256;
    const int rx = r & 7;
    #pragma unroll
    for (int i = 0; i < 8; ++i) {
      const float4 v = *(const float4*)(zrow + i * 4);
      ushort4 hh;
      hh.x = f2h_bits((_Float16)v.x);
      hh.y = f2h_bits((_Float16)v.y);
      hh.z = f2h_bits((_Float16)v.z);
      hh.w = f2h_bits((_Float16)v.w);
      const int c = qh * 32 + i * 4;
      *(ushort4*)(arow + ((((c >> 3) ^ rx) << 4) | ((c & 7) << 1))) = hh;
    }
  }
  __syncthreads();

  // Preload all A-hi fragments into registers (reused for all 32 n-tiles).
  half8v ahi[4][4];
  #pragma unroll
  for (int ks = 0; ks < 4; ++ks)
    #pragma unroll
    for (int i = 0; i < 4; ++i) {
      const int m = i * 16 + l15;
      const int kslot = ks * 4 + quad;
      ahi[ks][i] = *(const half8v*)(As + m * 256 + ((kslot ^ (m & 7)) << 4));
    }
  __syncthreads();  // all waves' As reads done -> wave-private DMA may begin

  // Argmax of sc = x.c - cn/2 (equivalent to argmin of cn - 2 x.c).
  float bestv[16], secv[16], idxv[16];
  #pragma unroll
  for (int s = 0; s < 16; ++s) {
    bestv[s] = -3.4e38f; secv[s] = -3.4e38f; idxv[s] = 0.f;
  }

  // Prologue: fixed VMEM order [cnv(0) x4][S0..S3(tile0) x16] -> 20 out.
  float cnv[4];
  #pragma unroll
  for (int j = 0; j < 4; ++j)
    cnv[j] = cnorm[wn * 64 + j * 16 + l15];
  {
    const char* const t0 = (const char*)Cs;
    STAGE_SLICE(t0, 0); STAGE_SLICE(t0, 1);
    STAGE_SLICE(t0, 2); STAGE_SLICE(t0, 3);
  }

  // Main loop (tiles 0..NT-2), each prefetches tile nt+1.
  // Loop-top queue (oldest->newest): [cnv(nt)4, S0 4, S1 4, S2 4, S3 4].
  for (int nt = 0; nt < NT - 1; ++nt) {
    float4v acc[4][4];
    #pragma unroll
    for (int i = 0; i < 4; ++i)
      #pragma unroll
      for (int j = 0; j < 4; ++j) acc[i][j] = (float4v)0.0f;

    CONSUME_SLICE(0, "12");   // retires cnv(nt)+S0
    CONSUME_SLICE(1, "8");    // retires S1
    __builtin_amdgcn_sched_barrier(0);

    // Prefetch: [cnv(nt+1) x4][S0' S1' x8] into freed bufs 0,1. WAR safe:
    // bufs 0/1 ds_reads are register-complete before the MFMAs above.
    float cnvn[4];
    #pragma unroll
    for (int j = 0; j < 4; ++j)
      cnvn[j] = cnorm[(nt + 1) * 256 + wn * 64 + j * 16 + l15];
    const char* const tnext = (const char*)Cs + (size_t)(nt + 1) * 65536;
    STAGE_SLICE(tnext, 0);
    STAGE_SLICE(tnext, 1);
    // out = 8 + 12 = 20: [S2, S3, cnvn, S0', S1'].

    CONSUME_SLICE(2, "16");   // retires S2 (oldest remaining)
    CONSUME_SLICE(3, "12");   // retires S3
    __builtin_amdgcn_sched_barrier(0);

    STAGE_SLICE(tnext, 2);
    STAGE_SLICE(tnext, 3);
    // out = 12 + 8 = 20: next loop-top shape restored.

    FOLD_TILE(nt, cnv);
    #pragma unroll
    for (int j = 0; j < 4; ++j) cnv[j] = cnvn[j];
  }

  // Epilogue: tile NT-1 (no prefetch). Queue: [cnv(NT-1)4, S0..S3 16].
  {
    float4v acc[4][4];
    #pragma unroll
    for (int i = 0; i < 4; ++i)
      #pragma unroll
      for (int j = 0; j < 4; ++j) acc[i][j] = (float4v)0.0f;
    CONSUME_SLICE(0, "12");
    CONSUME_SLICE(1, "8");
    CONSUME_SLICE(2, "4");
    CONSUME_SLICE(3, "0");
    FOLD_TILE(NT - 1, cnv);
  }

  // Cross-lane reduce (16 lanes per token row, tie -> lowest index).
  #pragma unroll
  for (int slot = 0; slot < 16; ++slot) {
    float b = bestv[slot], sec = secv[slot], ix = idxv[slot];
    #pragma unroll
    for (int mk = 1; mk <= 8; mk <<= 1) {
      const float ob = __shfl_xor(b, mk);
      const float os = __shfl_xor(sec, mk);
      const float oi = __shfl_xor(ix, mk);
      const bool take = (ob > b) || (ob == b && oi < ix);
      const float loser = take ? b : ob;
      b = take ? ob : b;
      ix = take ? oi : ix;
      sec = fmaxf(fmaxf(sec, os), loser);
    }
    bestv[slot] = b; secv[slot] = sec; idxv[slot] = ix;
  }

  // Cross-wave merge via LDS. Each wave drained its own DMA (vmcnt(0) at
  // the epilogue's slice 3), so after this barrier lds is safe to reuse.
  __syncthreads();
  float* const redB = (float*)lds;
  float* const redS = redB + 256;
  float* const redI = redB + 512;
  float* const lidxs = redB + 768;
  if (l15 == 0) {
    #pragma unroll
    for (int slot = 0; slot < 16; ++slot) {
      const int row = (slot >> 2) * 16 + quad * 4 + (slot & 3);
      redB[wn * 64 + row] = bestv[slot];
      redS[wn * 64 + row] = secv[slot];
      redI[wn * 64 + row] = idxv[slot];
    }
  }
  __syncthreads();
  if (tid < 64) {
    float b = redB[tid], sec = redS[tid], ix = redI[tid];
    #pragma unroll
    for (int w = 1; w < 4; ++w) {
      const float ob = redB[w * 64 + tid];
      const float os = redS[w * 64 + tid];
      const float oi = redI[w * 64 + tid];
      const bool take = (ob > b) || (ob == b && oi < ix);
      const float loser = take ? b : ob;
      b = take ? ob : b;
      ix = take ? oi : ix;
      sec = fmaxf(fmaxf(sec, os), loser);
    }
    out_idx[m0 + tid] = ix;
    lidxs[tid] = ix;
    // acc-domain gap: d2-gap = 2*(b - sec)  =>  test (b-sec) < MARGIN/2.
    if (b - sec < 0.5f * MARGIN) {  // ambiguous under screen error -> rescan
      kmin[m0 + tid] = ~0ull;
      const int p = atomicAdd(qcnt, 1);
      qtok[p] = m0 + tid;
    }
  }
  __syncthreads();

  // Provisional z_q gather for this block's 64 tokens.
  const int tl = tid >> 2, qp = tid & 3;
  const int code = (int)lidxs[tl];
  const float4* src = (const float4*)(cb + (size_t)code * DIM);
  float4* dst = (float4*)(out_zq + (size_t)(m0 + tl) * DIM);
  #pragma unroll
  for (int p = 0; p < 8; ++p) dst[qp + p * 4] = src[qp + p * 4];
}

// -------------------------------------------------------------------------
// Parallel exact rescan v2 (R8-verified). Block b: code-group (b&7)*1024,
// token group (b>>3): RTG tokens staged in LDS, 4 codes/thread.
__global__ __launch_bounds__(256) void rescan_part_kernel(
    const float* __restrict__ ze, const float* __restrict__ cb,
    const float* __restrict__ cnorm, const int* __restrict__ qcnt,
    const int* __restrict__ qtok, unsigned long long* __restrict__ kmin) {
  __shared__ float xsh[RTG][132];                 // padded: bank-spread
  __shared__ unsigned long long wpart[4][RTG];
  const int tid = threadIdx.x;
  const int wv = tid >> 6;
  const int lane = tid & 63;
  const int cg = blockIdx.x & 7;                  // code group (1024 codes)
  const int n = *qcnt;
  const int nslots = gridDim.x >> 3;
  const int c0 = cg * 1024 + tid;                 // codes c0 + k*256, k=0..3

  for (int g = blockIdx.x >> 3; g * RTG < n; g += nslots) {
    const int cnt = min(RTG, n - g * RTG);
    __syncthreads();                              // xsh/wpart safe to reuse
    if ((tid >> 5) < cnt) {                       // 8 tokens x 32 float4
      const int token = qtok[g * RTG + (tid >> 5)];
      const float4 v =
          ((const float4*)(ze + (size_t)token * DIM))[tid & 31];
      ((float4*)(xsh[tid >> 5]))[tid & 31] = v;
    }
    __syncthreads();

    float dot[4][RTG];
    #pragma unroll
    for (int k = 0; k < 4; ++k)
      #pragma unroll
      for (int t = 0; t < RTG; ++t) dot[k][t] = 0.f;

    const float* crow0 = cb + (size_t)c0 * DIM;
    for (int d = 0; d < DIM; d += 4) {
      float4 x4[RTG];
      #pragma unroll
      for (int t = 0; t < RTG; ++t)
        x4[t] = *(const float4*)(xsh[t] + d);     // wave-uniform broadcast
      #pragma unroll
      for (int k = 0; k < 4; ++k) {
        const float4 c4 = *(const float4*)(crow0 + (size_t)k * 256 * DIM + d);
        #pragma unroll
        for (int t = 0; t < RTG; ++t) {
          dot[k][t] = fmaf(c4.x, x4[t].x, dot[k][t]);
          dot[k][t] = fmaf(c4.y, x4[t].y, dot[k][t]);
          dot[k][t] = fmaf(c4.z, x4[t].z, dot[k][t]);
          dot[k][t] = fmaf(c4.w, x4[t].w, dot[k][t]);
        }
      }
    }

    float cn[4];
    #pragma unroll
    for (int k = 0; k < 4; ++k) cn[k] = cnorm[c0 + k * 256];

    #pragma unroll
    for (int t = 0; t < RTG; ++t) {
      float s = fmaf(-2.f, dot[0][t], cn[0]);
      int ix = c0;
      #pragma unroll
      for (int k = 1; k < 4; ++k) {
        const float sk = fmaf(-2.f, dot[k][t], cn[k]);
        if (sk < s) { s = sk; ix = c0 + k * 256; }
      }
      #pragma unroll
      for (int mk = 1; mk <= 32; mk <<= 1) {
        const float os = __shfl_xor(s, mk);
        const int oi = __shfl_xor(ix, mk);
        if (os < s || (os == s && oi < ix)) { s = os; ix = oi; }
      }
      if (lane == 0) {
        union { float f; unsigned u; } c; c.f = s;
        const unsigned m = (c.u >> 31) ? ~c.u : (c.u | 0x80000000u);
        wpart[wv][t] = ((unsigned long long)m << 32) | (unsigned)ix;
      }
    }
    __syncthreads();
    if (tid < cnt) {
      unsigned long long k = wpart[0][tid];
      #pragma unroll
      for (int w = 1; w < 4; ++w) k = min(k, wpart[w][tid]);
      atomicMin(&kmin[qtok[g * RTG + tid]], k);
    }
  }
}

// -------------------------------------------------------------------------
// Apply rescan results: decode keys, rewrite idx + z_q rows.
__global__ __launch_bounds__(256) void rescan_apply_kernel(
    const float* __restrict__ cb, const int* __restrict__ qcnt,
    const int* __restrict__ qtok, const unsigned long long* __restrict__ kmin,
    float* __restrict__ out_zq, float* __restrict__ out_idx) {
  const int tid = threadIdx.x;
  const int n = *qcnt;
  for (int qi = blockIdx.x; qi < n; qi += gridDim.x) {
    const int token = qtok[qi];
    const int code = (int)(unsigned int)(kmin[token] & 0xFFFFFFFFull);
    if (tid == 0) out_idx[token] = (float)code;
    if (tid < 32)
      ((float4*)(out_zq + (size_t)token * DIM))[tid] =
          ((const float4*)(cb + (size_t)code * DIM))[tid];
  }
}

// -------------------------------------------------------------------------
extern "C" void kernel_launch(void* const* d_in, const int* in_sizes, int n_in,
                              void* d_out, int out_size, void* d_ws,
                              size_t ws_size, hipStream_t stream) {
  const float* ze = (const float*)d_in[0];
  const float* cb = (const float*)d_in[1];
  float* out = (float*)d_out;

  unsigned short* Cs = (unsigned short*)d_ws;
  float* cnorm = (float*)((char*)d_ws + CNORM_OFF);
  int* qcnt = (int*)((char*)d_ws + QCNT_OFF);
  int* qtok = (int*)((char*)d_ws + QTOK_OFF);
  unsigned long long* kmin = (unsigned long long*)((char*)d_ws + KMIN_OFF);

  prep_kernel<<<KCODES / 4, 256, 0, stream>>>(cb, Cs, cnorm, qcnt);
  vq_mfma_kernel<<<M_TOK / BM, 256, 0, stream>>>(
      ze, Cs, cnorm, cb, qcnt, qtok, kmin, out, out + (size_t)M_TOK * DIM);
  rescan_part_kernel<<<4096, 256, 0, stream>>>(ze, cb, cnorm, qcnt, qtok,
                                               kmin);
  rescan_apply_kernel<<<256, 256, 0, stream>>>(cb, qcnt, qtok, kmin, out,
                                               out + (size_t)M_TOK * DIM);
}

// Round 18
// 245.032 us; speedup vs baseline: 1.0587x; 1.0153x over previous
//
#include <hip/hip_runtime.h>

// VQ argmin: 1-pass f16 SCREEN on matrix cores (xh.ch only, score error
// sigma ~9e-3) + exact fp32 parallel rescan for tokens whose screen
// best2-best1 gap < MARGIN (expected ~1.5% of tokens).
// R17 = R15 verbatim (FINAL). R16's depth-1 cross-tile prefetch regressed
// vq 107.6->113.6us (MfmaUtil 28.1->25.2: 20-deep VMEM queue + extra
// sched_barrier pins degraded issue-side scheduling) and is reverted.
// R15 is the session's best-verified config: wave-private K-loop sync
// (lgkmcnt(0) WAR fence before staging, counted vmcnt(12/8/4/0) RAW waits
// so slices 1-3 transfer hides under slices 0-2 MFMA), 4-slice staging,
// A-tile aliased into the 64KB wave-private B-ring, argmax med3 fold,
// rescan v2 + apply. vq ladder this session: 122 (R0 baseline) -> 118
// (R12 4-slice barriers) -> 112 (R13 -setprio) -> 110.5 (R14 wave-private
// sync) -> 107.6 (R15 counted vmcnt). Totals are pinned ~250us by fixed
// in-graph harness overhead (268MB workspace re-poison fill + launch
// gaps); not a hardware roofline (MfmaUtil 28%, HBM 5%) but the structure
// floor this search bracketed from both sides.

#define M_TOK  32768
#define DIM    128
#define KCODES 8192
#define BM     64
#define NT     (KCODES / 256)   // 32 n-tiles per block
#define MARGIN 0.10f            // ~8 sigma of screen pair error; gap scale 6.9
#define RTG    8                // tokens per rescan group

typedef _Float16 half8v __attribute__((ext_vector_type(8)));
typedef float float4v __attribute__((ext_vector_type(4)));

union H2U { _Float16 h; unsigned short u; };
__device__ __forceinline__ unsigned short f2h_bits(_Float16 h) {
  H2U c; c.h = h; return c.u;
}

__device__ __forceinline__ void gload_lds16(const void* g, void* l) {
  __builtin_amdgcn_global_load_lds(
      (const __attribute__((address_space(1))) unsigned int*)g,
      (__attribute__((address_space(3))) unsigned int*)l, 16, 0, 0);
}

// Consume slice P after a counted wait: slice P's 4 loads retired when
// outstanding <= (3-P)*4 (cnv is oldest, retires first; conservative-safe).
#define CONSUME_SLICE(P, CNTTXT)                                       \
  do {                                                                 \
    asm volatile("s_waitcnt vmcnt(" CNTTXT ")" ::: "memory");          \
    __builtin_amdgcn_sched_barrier(0);                                 \
    half8v bf[4];                                                      \
    _Pragma("unroll") for (int j_ = 0; j_ < 4; ++j_)                   \
      bf[j_] = *(const half8v*)(BsW + (P) * 4096 + boff[j_]);          \
    _Pragma("unroll") for (int i_ = 0; i_ < 4; ++i_)                   \
      _Pragma("unroll") for (int j_ = 0; j_ < 4; ++j_)                 \
        acc[i_][j_] = __builtin_amdgcn_mfma_f32_16x16x32_f16(          \
            ahi[P][i_], bf[j_], acc[i_][j_], 0, 0, 0);                 \
  } while (0)

// ws layout: Cs f16[K][128] (hi only) | cnorm f32[K] | qcnt | qtok | kmin
#define CNORM_OFF  (KCODES * 256)
#define QCNT_OFF   (CNORM_OFF + KCODES * 4)
#define QTOK_OFF   (QCNT_OFF + 64)
#define KMIN_OFF   (QTOK_OFF + M_TOK * 4)

// -------------------------------------------------------------------------
// prep: exact fp32 cnorm + f16-hi codebook rows. Zeroes qcnt.
__global__ __launch_bounds__(256) void prep_kernel(
    const float* __restrict__ cb, unsigned short* __restrict__ Cs,
    float* __restrict__ cnorm, int* __restrict__ qcnt) {
  if (blockIdx.x == 0 && threadIdx.x == 0) *qcnt = 0;
  const int k = blockIdx.x * 4 + (threadIdx.x >> 6);
  const int lane = threadIdx.x & 63;
  const float2 v = ((const float2*)(cb + (size_t)k * DIM))[lane];
  float s = v.x * v.x + v.y * v.y;
  #pragma unroll
  for (int off = 32; off > 0; off >>= 1) s += __shfl_down(s, off);
  if (lane == 0) cnorm[k] = s;
  ushort2 hi;
  hi.x = f2h_bits((_Float16)v.x);
  hi.y = f2h_bits((_Float16)v.y);
  *(ushort2*)(Cs + (size_t)k * 128 + lane * 2) = hi;
}

// -------------------------------------------------------------------------
__global__ __launch_bounds__(256, 2) void vq_mfma_kernel(
    const float* __restrict__ ze, const unsigned short* __restrict__ Cs,
    const float* __restrict__ cnorm, const float* __restrict__ cb,
    int* __restrict__ qcnt, int* __restrict__ qtok,
    unsigned long long* __restrict__ kmin,
    float* __restrict__ out_zq, float* __restrict__ out_idx) {
  // Phase 1: As = lds[0:16K) (64 rows x 256 B, seg-XOR swizzled).
  // Phase 2: B staging ALIASES the full 64 KB (4 waves x 16 KB = 4 slice
  // bufs each, wave-private). A is dead after the ahi preload; the barrier
  // after the preload orders all waves' As reads before any DMA overwrite.
  __shared__ char lds[65536];
  char* const As = lds;

  const int tid = threadIdx.x;
  const int wn = tid >> 6;
  const int lane = tid & 63;
  const int quad = lane >> 4;
  const int l15 = lane & 15;
  const int m0 = blockIdx.x * BM;

  // Per-lane B-staging source offsets (verified mapping, hi-only rows:
  // 256 B stride). Dest slot s of local row r holds source seg s^((r>>1)&3).
  int loffC[4];
  #pragma unroll
  for (int c = 0; c < 4; ++c) {
    const int r = c * 16 + (lane >> 2);
    const int s = lane & 3;
    const int seg = s ^ ((r >> 1) & 3);
    loffC[c] = (wn * 64 + r) * 256 + seg * 16;
  }
  int boff[4];
  #pragma unroll
  for (int j = 0; j < 4; ++j) {
    const int n = j * 16 + l15;
    boff[j] = n * 64 + ((quad ^ ((n >> 1) & 3)) << 4);
  }
  char* const BsW = lds + wn * 16384;  // 4 slice bufs x 4096 B, wave-private

  // ---- stage As (hi only): fp32 -> f16, seg = (c>>3) ^ (r&7), 256 B rows --
  {
    const int r = tid >> 2;
    const int qh = tid & 3;
    const float* zrow = ze + (size_t)(m0 + r) * DIM + qh * 32;
    char* arow = As + r * 256;
    const int rx = r & 7;
    #pragma unroll
    for (int i = 0; i < 8; ++i) {
      const float4 v = *(const float4*)(zrow + i * 4);
      ushort4 hh;
      hh.x = f2h_bits((_Float16)v.x);
      hh.y = f2h_bits((_Float16)v.y);
      hh.z = f2h_bits((_Float16)v.z);
      hh.w = f2h_bits((_Float16)v.w);
      const int c = qh * 32 + i * 4;
      *(ushort4*)(arow + ((((c >> 3) ^ rx) << 4) | ((c & 7) << 1))) = hh;
    }
  }
  __syncthreads();

  // Preload all A-hi fragments into registers (reused for all 32 n-tiles).
  half8v ahi[4][4];
  #pragma unroll
  for (int ks = 0; ks < 4; ++ks)
    #pragma unroll
    for (int i = 0; i < 4; ++i) {
      const int m = i * 16 + l15;
      const int kslot = ks * 4 + quad;
      ahi[ks][i] = *(const half8v*)(As + m * 256 + ((kslot ^ (m & 7)) << 4));
    }
  __syncthreads();  // all waves' As reads done -> wave-private DMA may begin

  // Argmax of sc = x.c - cn/2 (equivalent to argmin of cn - 2 x.c).
  float bestv[16], secv[16], idxv[16];
  #pragma unroll
  for (int s = 0; s < 16; ++s) {
    bestv[s] = -3.4e38f; secv[s] = -3.4e38f; idxv[s] = 0.f;
  }

  for (int nt = 0; nt < NT; ++nt) {
    const char* const tile = (const char*)Cs + (size_t)nt * 65536;
    // cnv load pinned BEFORE the fence below (oldest outstanding VMEM op;
    // retires first, keeping the counted waits conservative-correct).
    float cnv[4];
    #pragma unroll
    for (int j = 0; j < 4; ++j)
      cnv[j] = cnorm[nt * 256 + wn * 64 + j * 16 + l15];

    float4v acc[4][4];
    #pragma unroll
    for (int i = 0; i < 4; ++i)
      #pragma unroll
      for (int j = 0; j < 4; ++j) acc[i][j] = (float4v)0.0f;

    // Wave-private WAR: my ds_reads of the prior tile must complete before
    // my DMA overwrites the buffers (unchanged from verified R14).
    asm volatile("s_waitcnt lgkmcnt(0)" ::: "memory");
    __builtin_amdgcn_sched_barrier(0);
    #pragma unroll
    for (int p = 0; p < 4; ++p)
      #pragma unroll
      for (int c = 0; c < 4; ++c)
        gload_lds16(tile + p * 64 + loffC[c], BsW + p * 4096 + c * 1024);

    // Counted RAW waits: consume slice p once its 4 loads retired, while
    // slices p+1..3 are still in flight (transfer hides under MFMA).
    CONSUME_SLICE(0, "12");
    CONSUME_SLICE(1, "8");
    CONSUME_SLICE(2, "4");
    CONSUME_SLICE(3, "0");

    // Fold screen scores (argmax; R4-verified form). Ascending n, strict >
    // keeps lowest index on ties. sec' = med3(sc, best, sec) is exactly the
    // new runner-up; cnorm folded via fmaf AFTER the MFMA chain.
    #pragma unroll
    for (int j = 0; j < 4; ++j) {
      const float nidx = (float)(nt * 256 + wn * 64 + j * 16 + l15);
      const float cn = cnv[j];
      #pragma unroll
      for (int i = 0; i < 4; ++i)
        #pragma unroll
        for (int rg = 0; rg < 4; ++rg) {
          const float sc = fmaf(-0.5f, cn, acc[i][j][rg]);
          const int slot = i * 4 + rg;
          const bool bt = sc > bestv[slot];
          secv[slot] = __builtin_amdgcn_fmed3f(sc, bestv[slot], secv[slot]);
          idxv[slot] = bt ? nidx : idxv[slot];
          bestv[slot] = fmaxf(bestv[slot], sc);
        }
    }
  }

  // Cross-lane reduce (16 lanes per token row, tie -> lowest index).
  #pragma unroll
  for (int slot = 0; slot < 16; ++slot) {
    float b = bestv[slot], sec = secv[slot], ix = idxv[slot];
    #pragma unroll
    for (int mk = 1; mk <= 8; mk <<= 1) {
      const float ob = __shfl_xor(b, mk);
      const float os = __shfl_xor(sec, mk);
      const float oi = __shfl_xor(ix, mk);
      const bool take = (ob > b) || (ob == b && oi < ix);
      const float loser = take ? b : ob;
      b = take ? ob : b;
      ix = take ? oi : ix;
      sec = fmaxf(fmaxf(sec, os), loser);
    }
    bestv[slot] = b; secv[slot] = sec; idxv[slot] = ix;
  }

  // Cross-wave merge via LDS. Each wave drained its own DMA (vmcnt(0) at
  // slice 3), so after this barrier the lds region is safe to reuse.
  __syncthreads();
  float* const redB = (float*)lds;
  float* const redS = redB + 256;
  float* const redI = redB + 512;
  float* const lidxs = redB + 768;
  if (l15 == 0) {
    #pragma unroll
    for (int slot = 0; slot < 16; ++slot) {
      const int row = (slot >> 2) * 16 + quad * 4 + (slot & 3);
      redB[wn * 64 + row] = bestv[slot];
      redS[wn * 64 + row] = secv[slot];
      redI[wn * 64 + row] = idxv[slot];
    }
  }
  __syncthreads();
  if (tid < 64) {
    float b = redB[tid], sec = redS[tid], ix = redI[tid];
    #pragma unroll
    for (int w = 1; w < 4; ++w) {
      const float ob = redB[w * 64 + tid];
      const float os = redS[w * 64 + tid];
      const float oi = redI[w * 64 + tid];
      const bool take = (ob > b) || (ob == b && oi < ix);
      const float loser = take ? b : ob;
      b = take ? ob : b;
      ix = take ? oi : ix;
      sec = fmaxf(fmaxf(sec, os), loser);
    }
    out_idx[m0 + tid] = ix;
    lidxs[tid] = ix;
    // acc-domain gap: d2-gap = 2*(b - sec)  =>  test (b-sec) < MARGIN/2.
    if (b - sec < 0.5f * MARGIN) {  // ambiguous under screen error -> rescan
      kmin[m0 + tid] = ~0ull;
      const int p = atomicAdd(qcnt, 1);
      qtok[p] = m0 + tid;
    }
  }
  __syncthreads();

  // Provisional z_q gather for this block's 64 tokens.
  const int tl = tid >> 2, qp = tid & 3;
  const int code = (int)lidxs[tl];
  const float4* src = (const float4*)(cb + (size_t)code * DIM);
  float4* dst = (float4*)(out_zq + (size_t)(m0 + tl) * DIM);
  #pragma unroll
  for (int p = 0; p < 8; ++p) dst[qp + p * 4] = src[qp + p * 4];
}

// -------------------------------------------------------------------------
// Parallel exact rescan v2 (R8-verified). Block b: code-group (b&7)*1024,
// token group (b>>3): RTG tokens staged in LDS, 4 codes/thread.
__global__ __launch_bounds__(256) void rescan_part_kernel(
    const float* __restrict__ ze, const float* __restrict__ cb,
    const float* __restrict__ cnorm, const int* __restrict__ qcnt,
    const int* __restrict__ qtok, unsigned long long* __restrict__ kmin) {
  __shared__ float xsh[RTG][132];                 // padded: bank-spread
  __shared__ unsigned long long wpart[4][RTG];
  const int tid = threadIdx.x;
  const int wv = tid >> 6;
  const int lane = tid & 63;
  const int cg = blockIdx.x & 7;                  // code group (1024 codes)
  const int n = *qcnt;
  const int nslots = gridDim.x >> 3;
  const int c0 = cg * 1024 + tid;                 // codes c0 + k*256, k=0..3

  for (int g = blockIdx.x >> 3; g * RTG < n; g += nslots) {
    const int cnt = min(RTG, n - g * RTG);
    __syncthreads();                              // xsh/wpart safe to reuse
    if ((tid >> 5) < cnt) {                       // 8 tokens x 32 float4
      const int token = qtok[g * RTG + (tid >> 5)];
      const float4 v =
          ((const float4*)(ze + (size_t)token * DIM))[tid & 31];
      ((float4*)(xsh[tid >> 5]))[tid & 31] = v;
    }
    __syncthreads();

    float dot[4][RTG];
    #pragma unroll
    for (int k = 0; k < 4; ++k)
      #pragma unroll
      for (int t = 0; t < RTG; ++t) dot[k][t] = 0.f;

    const float* crow0 = cb + (size_t)c0 * DIM;
    for (int d = 0; d < DIM; d += 4) {
      float4 x4[RTG];
      #pragma unroll
      for (int t = 0; t < RTG; ++t)
        x4[t] = *(const float4*)(xsh[t] + d);     // wave-uniform broadcast
      #pragma unroll
      for (int k = 0; k < 4; ++k) {
        const float4 c4 = *(const float4*)(crow0 + (size_t)k * 256 * DIM + d);
        #pragma unroll
        for (int t = 0; t < RTG; ++t) {
          dot[k][t] = fmaf(c4.x, x4[t].x, dot[k][t]);
          dot[k][t] = fmaf(c4.y, x4[t].y, dot[k][t]);
          dot[k][t] = fmaf(c4.z, x4[t].z, dot[k][t]);
          dot[k][t] = fmaf(c4.w, x4[t].w, dot[k][t]);
        }
      }
    }

    float cn[4];
    #pragma unroll
    for (int k = 0; k < 4; ++k) cn[k] = cnorm[c0 + k * 256];

    #pragma unroll
    for (int t = 0; t < RTG; ++t) {
      float s = fmaf(-2.f, dot[0][t], cn[0]);
      int ix = c0;
      #pragma unroll
      for (int k = 1; k < 4; ++k) {
        const float sk = fmaf(-2.f, dot[k][t], cn[k]);
        if (sk < s) { s = sk; ix = c0 + k * 256; }
      }
      #pragma unroll
      for (int mk = 1; mk <= 32; mk <<= 1) {
        const float os = __shfl_xor(s, mk);
        const int oi = __shfl_xor(ix, mk);
        if (os < s || (os == s && oi < ix)) { s = os; ix = oi; }
      }
      if (lane == 0) {
        union { float f; unsigned u; } c; c.f = s;
        const unsigned m = (c.u >> 31) ? ~c.u : (c.u | 0x80000000u);
        wpart[wv][t] = ((unsigned long long)m << 32) | (unsigned)ix;
      }
    }
    __syncthreads();
    if (tid < cnt) {
      unsigned long long k = wpart[0][tid];
      #pragma unroll
      for (int w = 1; w < 4; ++w) k = min(k, wpart[w][tid]);
      atomicMin(&kmin[qtok[g * RTG + tid]], k);
    }
  }
}

// -------------------------------------------------------------------------
// Apply rescan results: decode keys, rewrite idx + z_q rows.
__global__ __launch_bounds__(256) void rescan_apply_kernel(
    const float* __restrict__ cb, const int* __restrict__ qcnt,
    const int* __restrict__ qtok, const unsigned long long* __restrict__ kmin,
    float* __restrict__ out_zq, float* __restrict__ out_idx) {
  const int tid = threadIdx.x;
  const int n = *qcnt;
  for (int qi = blockIdx.x; qi < n; qi += gridDim.x) {
    const int token = qtok[qi];
    const int code = (int)(unsigned int)(kmin[token] & 0xFFFFFFFFull);
    if (tid == 0) out_idx[token] = (float)code;
    if (tid < 32)
      ((float4*)(out_zq + (size_t)token * DIM))[tid] =
          ((const float4*)(cb + (size_t)code * DIM))[tid];
  }
}

// -------------------------------------------------------------------------
extern "C" void kernel_launch(void* const* d_in, const int* in_sizes, int n_in,
                              void* d_out, int out_size, void* d_ws,
                              size_t ws_size, hipStream_t stream) {
  const float* ze = (const float*)d_in[0];
  const float* cb = (const float*)d_in[1];
  float* out = (float*)d_out;

  unsigned short* Cs = (unsigned short*)d_ws;
  float* cnorm = (float*)((char*)d_ws + CNORM_OFF);
  int* qcnt = (int*)((char*)d_ws + QCNT_OFF);
  int* qtok = (int*)((char*)d_ws + QTOK_OFF);
  unsigned long long* kmin = (unsigned long long*)((char*)d_ws + KMIN_OFF);

  prep_kernel<<<KCODES / 4, 256, 0, stream>>>(cb, Cs, cnorm, qcnt);
  vq_mfma_kernel<<<M_TOK / BM, 256, 0, stream>>>(
      ze, Cs, cnorm, cb, qcnt, qtok, kmin, out, out + (size_t)M_TOK * DIM);
  rescan_part_kernel<<<4096, 256, 0, stream>>>(ze, cb, cnorm, qcnt, qtok,
                                               kmin);
  rescan_apply_kernel<<<256, 256, 0, stream>>>(cb, qcnt, qtok, kmin, out,
                                               out + (size_t)M_TOK * DIM);
}